// Round 8
// baseline (571.441 us; speedup 1.0000x reference)
//
#include <hip/hip_runtime.h>
#include <hip/hip_cooperative_groups.h>

namespace cg = cooperative_groups;

#define ROWS 1024
#define COLS 1024
#define NN (ROWS*COLS)

// R13: persistent cooperative kernel. R6's verified wave-autonomous 32x32
// region structure (8x8 lanes x 4x4 cells, signed-link weights, rolled step
// loop, no LDS, no block barriers), but ALL 32 steps in ONE launch:
// 4 stages x 8 steps with grid.sync() between stages, q ping-ponged via
// qA/qB. Weights/runoff built once instead of 4x. Fallback to the verified
// 4-launch path if cooperative launch is rejected.
#define OT    16               // output tile per wave
#define HALO  8
#define TPD   (COLS/OT)        // 64 tiles per dimension
#define WPB   4                // waves per block
#define NT    (WPB*64)         // 256 threads
#define NBLK  ((TPD*TPD)/WPB)  // 1024 blocks  (= 4 blocks/CU x 256 CUs)

static constexpr float RHOG    = 1000.0f * 9.81f;
static constexpr float INV_SEC = 1.0f / 31556926.0f;
static constexpr float FLOWC   = 0.0405f;

__device__ __forceinline__ float4 gld4(const float* __restrict__ p, int g, bool in) {
    if (in) return *reinterpret_cast<const float4*>(p + g);
    return make_float4(0.f, 0.f, 0.f, 0.f);
}

// ---- prologue: phi, inv_total, runoff -------------------------------------
__global__ __launch_bounds__(256) void k_pre(
        const float* __restrict__ bed, const float* __restrict__ pw,
        const int* __restrict__ status,
        const float* __restrict__ melt, const float* __restrict__ area,
        float* __restrict__ phi, float* __restrict__ inv,
        float* __restrict__ runoff) {
    int i = blockIdx.x * 256 + threadIdx.x;
    int r = i >> 10, c = i & (COLS - 1);
    float p = RHOG * bed[i] + pw[i];
    float t = 0.f;
    if (c > 0)        t += fmaxf(p - (RHOG * bed[i - 1]    + pw[i - 1]),    0.f);
    if (c < COLS - 1) t += fmaxf(p - (RHOG * bed[i + 1]    + pw[i + 1]),    0.f);
    if (r > 0)        t += fmaxf(p - (RHOG * bed[i - COLS] + pw[i - COLS]), 0.f);
    if (r < ROWS - 1) t += fmaxf(p - (RHOG * bed[i + COLS] + pw[i + COLS]), 0.f);
    phi[i]    = p;
    inv[i]    = (status[i] == 0 && t > 0.f) ? (1.f / t) : 0.f;
    runoff[i] = melt[i] * area[i] * INV_SEC;
}

// ---- shared device body helpers -------------------------------------------
// (weights built exactly as in R6/R11, which passed the harness)

// ---- persistent cooperative kernel: 4 stages x 8 steps --------------------
__global__ __launch_bounds__(NT, 4) void k_coop(
        const float* __restrict__ phi_g, const float* __restrict__ inv_g,
        const float* __restrict__ run_g,
        float* __restrict__ qA, float* __restrict__ qB,
        float* __restrict__ out,
        const float* __restrict__ cond, const int* __restrict__ status) {
    const int tid  = threadIdx.x;
    const int lane = tid & 63;
    const int wid  = blockIdx.x * WPB + (tid >> 6);
    const int tr = wid >> 6, tc = wid & (TPD - 1);
    const int R0 = tr * OT - HALO, C0 = tc * OT - HALO;
    const int wr = lane >> 3, wc = lane & 7;            // 8 x 8 lane grid
    const int gr0 = R0 + wr * 4, gc0 = C0 + wc * 4;     // lane's 4x4 block

    const int upL = (wr > 0) ? lane - 8 : lane;
    const int dnL = (wr < 7) ? lane + 8 : lane;
    const int lfL = (wc > 0) ? lane - 1 : lane;
    const int rtL = (wc < 7) ? lane + 1 : lane;

    const bool cin = ((unsigned)gc0 < COLS);
    const bool central = (wr >= 2) & (wr < 6) & (wc >= 2) & (wc < 6);

    // ---- stage phi/inv for this lane's 4x4 cells --------------------------
    float ph[4][4], iv[4][4];
#pragma unroll
    for (int i = 0; i < 4; ++i) {
        bool in = ((unsigned)(gr0 + i) < ROWS) & cin;
        int  g  = (gr0 + i) * COLS + gc0;
        float4 p4 = gld4(phi_g, g, in);
        float4 i4 = gld4(inv_g, g, in);
        ph[i][0]=p4.x; ph[i][1]=p4.y; ph[i][2]=p4.z; ph[i][3]=p4.w;
        iv[i][0]=i4.x; iv[i][1]=i4.y; iv[i][2]=i4.z; iv[i][3]=i4.w;
    }

    // halo phi/inv via shuffles (setup only)
    float phU[4], phD[4], ivU[4], ivD[4], phL[4], phR[4], ivL[4], ivR[4];
#pragma unroll
    for (int j = 0; j < 4; ++j) {
        phU[j] = __shfl(ph[3][j], upL, 64);  ivU[j] = __shfl(iv[3][j], upL, 64);
        phD[j] = __shfl(ph[0][j], dnL, 64);  ivD[j] = __shfl(iv[0][j], dnL, 64);
    }
#pragma unroll
    for (int i = 0; i < 4; ++i) {
        phL[i] = __shfl(ph[i][3], lfL, 64);  ivL[i] = __shfl(iv[i][3], lfL, 64);
        phR[i] = __shfl(ph[i][0], rtL, 64);  ivR[i] = __shfl(iv[i][0], rtL, 64);
    }

    // ---- signed link weights (40 regs, persist across all 32 steps) -------
    float WH[4][4];   // west link of (i,j): (i,j-1)->(i,j)
    float WV[4][4];   // north link of (i,j): (i-1,j)->(i,j)
    float EH[4];      // east link of (i,3)
    float SV[4];      // south link of (3,j)
#pragma unroll
    for (int i = 0; i < 4; ++i)
#pragma unroll
        for (int j = 0; j < 4; ++j) {
            float pw_ = (j > 0) ? ph[i][j-1] : phL[i];
            float iw_ = (j > 0) ? iv[i][j-1] : ivL[i];
            float s   = pw_ - ph[i][j];
            WH[i][j]  = s * ((s > 0.f) ? iw_ : iv[i][j]);
            float pn_ = (i > 0) ? ph[i-1][j] : phU[j];
            float in_ = (i > 0) ? iv[i-1][j] : ivU[j];
            float sv  = pn_ - ph[i][j];
            WV[i][j]  = sv * ((sv > 0.f) ? in_ : iv[i][j]);
        }
#pragma unroll
    for (int i = 0; i < 4; ++i) {
        float s = ph[i][3] - phR[i];
        EH[i] = s * ((s > 0.f) ? iv[i][3] : ivR[i]);
    }
#pragma unroll
    for (int j = 0; j < 4; ++j) {
        float s = ph[3][j] - phD[j];
        SV[j] = s * ((s > 0.f) ? iv[3][j] : ivD[j]);
    }

    // ---- runoff; q0 = runoff ----------------------------------------------
    float q[4][4], ro[4][4];
#pragma unroll
    for (int i = 0; i < 4; ++i) {
        bool in = ((unsigned)(gr0 + i) < ROWS) & cin;
        int  g  = (gr0 + i) * COLS + gc0;
        float4 r4 = gld4(run_g, g, in);
        ro[i][0]=r4.x; ro[i][1]=r4.y; ro[i][2]=r4.z; ro[i][3]=r4.w;
        q[i][0]=r4.x;  q[i][1]=r4.y;  q[i][2]=r4.z;  q[i][3]=r4.w;
    }

    cg::grid_group gg = cg::this_grid();

    // ---- 4 stages x 8 Jacobi steps ---------------------------------------
#pragma unroll 1
    for (int stage = 0; stage < 4; ++stage) {
#pragma unroll 1
        for (int s = 0; s < HALO; ++s) {
            float u[4], d[4], l[4], r[4];
#pragma unroll
            for (int j = 0; j < 4; ++j) {
                u[j] = __shfl(q[3][j], upL, 64);
                d[j] = __shfl(q[0][j], dnL, 64);
            }
#pragma unroll
            for (int i = 0; i < 4; ++i) {
                l[i] = __shfl(q[i][3], lfL, 64);
                r[i] = __shfl(q[i][0], rtL, 64);
            }
            float nq[4][4];
#pragma unroll
            for (int i = 0; i < 4; ++i)
#pragma unroll
                for (int j = 0; j < 4; ++j) {
                    float qw = (j > 0) ? q[i][j-1] : l[i];
                    float qe = (j < 3) ? q[i][j+1] : r[i];
                    float qn = (i > 0) ? q[i-1][j] : u[j];
                    float qs = (i < 3) ? q[i+1][j] : d[j];
                    float We = (j < 3) ? WH[i][j+1] : EH[i];
                    float Ws = (i < 3) ? WV[i+1][j] : SV[j];
                    float a = ro[i][j];
                    a = fmaf(fmaxf(WH[i][j], 0.f), qw, a);
                    a = fmaf(fmaxf(-We,      0.f), qe, a);
                    a = fmaf(fmaxf(WV[i][j], 0.f), qn, a);
                    a = fmaf(fmaxf(-Ws,      0.f), qs, a);
                    nq[i][j] = a;
                }
#pragma unroll
            for (int i = 0; i < 4; ++i)
#pragma unroll
                for (int j = 0; j < 4; ++j) q[i][j] = nq[i][j];
        }

        if (stage < 3) {
            // central q -> ping-pong buffer; sync; reload full region
            float* dst = (stage & 1) ? qB : qA;
            if (central) {
#pragma unroll
                for (int i = 0; i < 4; ++i) {
                    int go = (gr0 + i) * COLS + gc0;       // in-grid for central
                    *reinterpret_cast<float4*>(dst + go) =
                        make_float4(q[i][0], q[i][1], q[i][2], q[i][3]);
                }
            }
            gg.sync();
            const float* src = (stage & 1) ? qB : qA;
#pragma unroll
            for (int i = 0; i < 4; ++i) {
                bool in = ((unsigned)(gr0 + i) < ROWS) & cin;
                int  g  = (gr0 + i) * COLS + gc0;
                float4 q4 = gld4(src, g, in);
                q[i][0]=q4.x; q[i][1]=q4.y; q[i][2]=q4.z; q[i][3]=q4.w;
            }
        } else if (central) {
            // epilogue: gradient, masked to core nodes
#pragma unroll
            for (int i = 0; i < 4; ++i) {
                int go = (gr0 + i) * COLS + gc0;
                float4 c4 = *reinterpret_cast<const float4*>(cond + go);
                int4 st   = *reinterpret_cast<const int4*>(status + go);
                float4 o;
                float t;
                t = q[i][0] * FLOWC * (c4.x * sqrtf(sqrtf(c4.x))); o.x = (st.x == 0) ? t * t : 0.f;
                t = q[i][1] * FLOWC * (c4.y * sqrtf(sqrtf(c4.y))); o.y = (st.y == 0) ? t * t : 0.f;
                t = q[i][2] * FLOWC * (c4.z * sqrtf(sqrtf(c4.z))); o.z = (st.z == 0) ? t * t : 0.f;
                t = q[i][3] * FLOWC * (c4.w * sqrtf(sqrtf(c4.w))); o.w = (st.w == 0) ? t * t : 0.f;
                *reinterpret_cast<float4*>(out + go) = o;
            }
        }
    }
}

// ---- fallback: R6's verified 4-launch step kernel -------------------------
template <bool FIRST, bool FINAL>
__global__ __launch_bounds__(NT, 3) void k_step(
        const float* __restrict__ phi_g, const float* __restrict__ inv_g,
        const float* __restrict__ run_g, const float* __restrict__ qin,
        float* __restrict__ qout,
        const float* __restrict__ cond, const int* __restrict__ status) {
    const int tid  = threadIdx.x;
    const int lane = tid & 63;
    const int wid  = blockIdx.x * WPB + (tid >> 6);
    const int tr = wid >> 6, tc = wid & (TPD - 1);
    const int R0 = tr * OT - HALO, C0 = tc * OT - HALO;
    const int wr = lane >> 3, wc = lane & 7;
    const int gr0 = R0 + wr * 4, gc0 = C0 + wc * 4;

    const int upL = (wr > 0) ? lane - 8 : lane;
    const int dnL = (wr < 7) ? lane + 8 : lane;
    const int lfL = (wc > 0) ? lane - 1 : lane;
    const int rtL = (wc < 7) ? lane + 1 : lane;

    const bool cin = ((unsigned)gc0 < COLS);

    float ph[4][4], iv[4][4];
#pragma unroll
    for (int i = 0; i < 4; ++i) {
        bool in = ((unsigned)(gr0 + i) < ROWS) & cin;
        int  g  = (gr0 + i) * COLS + gc0;
        float4 p4 = gld4(phi_g, g, in);
        float4 i4 = gld4(inv_g, g, in);
        ph[i][0]=p4.x; ph[i][1]=p4.y; ph[i][2]=p4.z; ph[i][3]=p4.w;
        iv[i][0]=i4.x; iv[i][1]=i4.y; iv[i][2]=i4.z; iv[i][3]=i4.w;
    }
    float phU[4], phD[4], ivU[4], ivD[4], phL[4], phR[4], ivL[4], ivR[4];
#pragma unroll
    for (int j = 0; j < 4; ++j) {
        phU[j] = __shfl(ph[3][j], upL, 64);  ivU[j] = __shfl(iv[3][j], upL, 64);
        phD[j] = __shfl(ph[0][j], dnL, 64);  ivD[j] = __shfl(iv[0][j], dnL, 64);
    }
#pragma unroll
    for (int i = 0; i < 4; ++i) {
        phL[i] = __shfl(ph[i][3], lfL, 64);  ivL[i] = __shfl(iv[i][3], lfL, 64);
        phR[i] = __shfl(ph[i][0], rtL, 64);  ivR[i] = __shfl(iv[i][0], rtL, 64);
    }
    float WH[4][4], WV[4][4], EH[4], SV[4];
#pragma unroll
    for (int i = 0; i < 4; ++i)
#pragma unroll
        for (int j = 0; j < 4; ++j) {
            float pw_ = (j > 0) ? ph[i][j-1] : phL[i];
            float iw_ = (j > 0) ? iv[i][j-1] : ivL[i];
            float s   = pw_ - ph[i][j];
            WH[i][j]  = s * ((s > 0.f) ? iw_ : iv[i][j]);
            float pn_ = (i > 0) ? ph[i-1][j] : phU[j];
            float in_ = (i > 0) ? iv[i-1][j] : ivU[j];
            float sv  = pn_ - ph[i][j];
            WV[i][j]  = sv * ((sv > 0.f) ? in_ : iv[i][j]);
        }
#pragma unroll
    for (int i = 0; i < 4; ++i) {
        float s = ph[i][3] - phR[i];
        EH[i] = s * ((s > 0.f) ? iv[i][3] : ivR[i]);
    }
#pragma unroll
    for (int j = 0; j < 4; ++j) {
        float s = ph[3][j] - phD[j];
        SV[j] = s * ((s > 0.f) ? iv[3][j] : ivD[j]);
    }
    float q[4][4], ro[4][4];
#pragma unroll
    for (int i = 0; i < 4; ++i) {
        bool in = ((unsigned)(gr0 + i) < ROWS) & cin;
        int  g  = (gr0 + i) * COLS + gc0;
        float4 r4 = gld4(run_g, g, in);
        ro[i][0]=r4.x; ro[i][1]=r4.y; ro[i][2]=r4.z; ro[i][3]=r4.w;
        if (FIRST) {
            q[i][0]=r4.x; q[i][1]=r4.y; q[i][2]=r4.z; q[i][3]=r4.w;
        } else {
            float4 q4 = gld4(qin, g, in);
            q[i][0]=q4.x; q[i][1]=q4.y; q[i][2]=q4.z; q[i][3]=q4.w;
        }
    }
#pragma unroll 1
    for (int s = 0; s < HALO; ++s) {
        float u[4], d[4], l[4], r[4];
#pragma unroll
        for (int j = 0; j < 4; ++j) {
            u[j] = __shfl(q[3][j], upL, 64);
            d[j] = __shfl(q[0][j], dnL, 64);
        }
#pragma unroll
        for (int i = 0; i < 4; ++i) {
            l[i] = __shfl(q[i][3], lfL, 64);
            r[i] = __shfl(q[i][0], rtL, 64);
        }
        float nq[4][4];
#pragma unroll
        for (int i = 0; i < 4; ++i)
#pragma unroll
            for (int j = 0; j < 4; ++j) {
                float qw = (j > 0) ? q[i][j-1] : l[i];
                float qe = (j < 3) ? q[i][j+1] : r[i];
                float qn = (i > 0) ? q[i-1][j] : u[j];
                float qs = (i < 3) ? q[i+1][j] : d[j];
                float We = (j < 3) ? WH[i][j+1] : EH[i];
                float Ws = (i < 3) ? WV[i+1][j] : SV[j];
                float a = ro[i][j];
                a = fmaf(fmaxf(WH[i][j], 0.f), qw, a);
                a = fmaf(fmaxf(-We,      0.f), qe, a);
                a = fmaf(fmaxf(WV[i][j], 0.f), qn, a);
                a = fmaf(fmaxf(-Ws,      0.f), qs, a);
                nq[i][j] = a;
            }
#pragma unroll
        for (int i = 0; i < 4; ++i)
#pragma unroll
            for (int j = 0; j < 4; ++j) q[i][j] = nq[i][j];
    }
    if ((wr >= 2) & (wr < 6) & (wc >= 2) & (wc < 6)) {
#pragma unroll
        for (int i = 0; i < 4; ++i) {
            int go = (gr0 + i) * COLS + gc0;
            if (FINAL) {
                float4 c4 = *reinterpret_cast<const float4*>(cond + go);
                int4 st   = *reinterpret_cast<const int4*>(status + go);
                float4 o;
                float t;
                t = q[i][0] * FLOWC * (c4.x * sqrtf(sqrtf(c4.x))); o.x = (st.x == 0) ? t * t : 0.f;
                t = q[i][1] * FLOWC * (c4.y * sqrtf(sqrtf(c4.y))); o.y = (st.y == 0) ? t * t : 0.f;
                t = q[i][2] * FLOWC * (c4.z * sqrtf(sqrtf(c4.z))); o.z = (st.z == 0) ? t * t : 0.f;
                t = q[i][3] * FLOWC * (c4.w * sqrtf(sqrtf(c4.w))); o.w = (st.w == 0) ? t * t : 0.f;
                *reinterpret_cast<float4*>(qout + go) = o;
            } else {
                *reinterpret_cast<float4*>(qout + go) =
                    make_float4(q[i][0], q[i][1], q[i][2], q[i][3]);
            }
        }
    }
}

extern "C" void kernel_launch(void* const* d_in, const int* in_sizes, int n_in,
                              void* d_out, int out_size, void* d_ws, size_t ws_size,
                              hipStream_t stream) {
    const float* melt   = (const float*)d_in[0];
    const float* bed    = (const float*)d_in[1];
    const float* pw     = (const float*)d_in[2];
    const float* area   = (const float*)d_in[3];
    const float* cond   = (const float*)d_in[4];
    const int*   status = (const int*)d_in[5];
    float* out = (float*)d_out;

    char* ws = (char*)d_ws;
    float* phi    = (float*)(ws);                 //  4 MB
    float* inv    = (float*)(ws + 4ull  * NN);    //  4 MB
    float* runoff = (float*)(ws + 8ull  * NN);    //  4 MB
    float* qA     = (float*)(ws + 12ull * NN);    //  4 MB
    float* qB     = (float*)(ws + 16ull * NN);    //  4 MB (20 MB total)

    k_pre<<<dim3(NN / 256), dim3(256), 0, stream>>>(bed, pw, status, melt, area,
                                                    phi, inv, runoff);

    void* kargs[] = {
        (void*)&phi, (void*)&inv, (void*)&runoff,
        (void*)&qA,  (void*)&qB,  (void*)&out,
        (void*)&cond, (void*)&status
    };
    hipError_t e = hipLaunchCooperativeKernel((const void*)k_coop,
                                              dim3(NBLK), dim3(NT),
                                              kargs, 0, stream);
    if (e != hipSuccess) {
        // fallback: verified 4-launch path (R6)
        dim3 grid(NBLK), block(NT);
        k_step<true,  false><<<grid, block, 0, stream>>>(phi, inv, runoff, runoff, qA, nullptr, nullptr);
        k_step<false, false><<<grid, block, 0, stream>>>(phi, inv, runoff, qA, qB, nullptr, nullptr);
        k_step<false, false><<<grid, block, 0, stream>>>(phi, inv, runoff, qB, qA, nullptr, nullptr);
        k_step<false, true ><<<grid, block, 0, stream>>>(phi, inv, runoff, qA, out, cond, status);
    }
}